// Round 3
// baseline (1321.084 us; speedup 1.0000x reference)
//
#include <hip/hip_runtime.h>

#define N_NODES 500000
#define N_EDGES 5000000
#define D 16

#define SCAN_CHUNK 1024                     // elements per scan block (256 thr * 4)
#define NSCAN_BLOCKS ((N_NODES + SCAN_CHUNK - 1) / SCAN_CHUNK)   // 489

// ---------------------------------------------------------------------------
// 1) Histogram of destination degrees: deg[dst[e]]++
// ---------------------------------------------------------------------------
__global__ __launch_bounds__(256) void hist_kernel(
    const int* __restrict__ edge_index, int* __restrict__ deg) {
    int e = blockIdx.x * 256 + threadIdx.x;
    if (e < N_EDGES) atomicAdd(&deg[edge_index[N_EDGES + e]], 1);
}

// ---------------------------------------------------------------------------
// 2a) Per-block exclusive scan over SCAN_CHUNK elements; emit block totals.
// ---------------------------------------------------------------------------
__global__ __launch_bounds__(256) void scan_blocks_kernel(
    const int* __restrict__ deg, int* __restrict__ scanned,
    int* __restrict__ partials) {
    __shared__ int sdata[256];
    int t = threadIdx.x;
    int base = blockIdx.x * SCAN_CHUNK + t * 4;
    int v0 = 0, v1 = 0, v2 = 0, v3 = 0;
    if (base + 0 < N_NODES) v0 = deg[base + 0];
    if (base + 1 < N_NODES) v1 = deg[base + 1];
    if (base + 2 < N_NODES) v2 = deg[base + 2];
    if (base + 3 < N_NODES) v3 = deg[base + 3];
    int tsum = v0 + v1 + v2 + v3;
    sdata[t] = tsum;
    __syncthreads();
    for (int off = 1; off < 256; off <<= 1) {
        int val = (t >= off) ? sdata[t - off] : 0;
        __syncthreads();
        if (t >= off) sdata[t] += val;
        __syncthreads();
    }
    int excl = sdata[t] - tsum;   // exclusive prefix of this thread's 4 elems
    if (t == 255) partials[blockIdx.x] = sdata[255];
    int p = excl;
    if (base + 0 < N_NODES) scanned[base + 0] = p; p += v0;
    if (base + 1 < N_NODES) scanned[base + 1] = p; p += v1;
    if (base + 2 < N_NODES) scanned[base + 2] = p; p += v2;
    if (base + 3 < N_NODES) scanned[base + 3] = p;
}

// ---------------------------------------------------------------------------
// 2b) Exclusive scan of the (<=512) block totals, single block.
// ---------------------------------------------------------------------------
__global__ __launch_bounds__(512) void scan_partials_kernel(int* __restrict__ partials) {
    __shared__ int sdata[512];
    int t = threadIdx.x;
    int v = (t < NSCAN_BLOCKS) ? partials[t] : 0;
    sdata[t] = v;
    __syncthreads();
    for (int off = 1; off < 512; off <<= 1) {
        int val = (t >= off) ? sdata[t - off] : 0;
        __syncthreads();
        if (t >= off) sdata[t] += val;
        __syncthreads();
    }
    if (t < NSCAN_BLOCKS) partials[t] = sdata[t] - v;  // exclusive
}

// ---------------------------------------------------------------------------
// 2c) Add block offsets -> rowptr; duplicate into cursor; set rowptr[N]=E.
// ---------------------------------------------------------------------------
__global__ __launch_bounds__(256) void scan_add_kernel(
    const int* __restrict__ scanned, const int* __restrict__ partials,
    int* __restrict__ rowptr, int* __restrict__ cursor) {
    int i = blockIdx.x * 256 + threadIdx.x;
    if (i < N_NODES) {
        int v = scanned[i] + partials[i / SCAN_CHUNK];
        rowptr[i] = v;
        cursor[i] = v;
    }
    if (i == 0) rowptr[N_NODES] = N_EDGES;
}

// ---------------------------------------------------------------------------
// 3) Reorder: csr_src[pos] = src[e], pos = cursor[dst[e]]++
// ---------------------------------------------------------------------------
__global__ __launch_bounds__(256) void reorder_kernel(
    const int* __restrict__ edge_index, int* __restrict__ cursor,
    int* __restrict__ csr_src) {
    int e = blockIdx.x * 256 + threadIdx.x;
    if (e >= N_EDGES) return;
    int s = edge_index[e];
    int t = edge_index[N_EDGES + e];
    int pos = atomicAdd(&cursor[t], 1);
    csr_src[pos] = s;
}

// ---------------------------------------------------------------------------
// 4) Fused gather + GraphConv layer 1 (+ReLU):
//    h[i] = relu( (sum_{j->i} x[j]) @ Wrel^T + b + x[i] @ Wroot^T )
//    Block = 256 threads = 16 nodes; 16 lanes per node (one per feature dim).
// ---------------------------------------------------------------------------
__global__ __launch_bounds__(256) void gather_node1_kernel(
    const float* __restrict__ x,
    const int* __restrict__ rowptr, const int* __restrict__ csr_src,
    const float* __restrict__ w_rel, const float* __restrict__ b_rel,
    const float* __restrict__ w_root, float* __restrict__ h) {
    __shared__ float sWrelT[D * D];   // transposed: [k][dd]
    __shared__ float sWrootT[D * D];
    __shared__ float sB[D];
    __shared__ float sAgg[16][D + 1];
    __shared__ float sX[16][D + 1];

    {
        int r = threadIdx.x >> 4, c = threadIdx.x & 15;
        sWrelT[c * D + r] = w_rel[r * D + c];     // coalesced read, transposed store
        sWrootT[c * D + r] = w_root[r * D + c];
        if (threadIdx.x < D) sB[threadIdx.x] = b_rel[threadIdx.x];
    }
    __syncthreads();

    int g = threadIdx.x >> 4;      // node slot in block
    int d = threadIdx.x & 15;      // feature dim
    int node = blockIdx.x * 16 + g;

    if (node < N_NODES) {
        int r0 = rowptr[node], r1 = rowptr[node + 1];
        float acc = 0.f;
        for (int j = r0; j < r1; ++j) {
            int s = csr_src[j];                 // broadcast within 16-lane group
            acc += x[(long)s * D + d];          // 64B coalesced per group
        }
        sAgg[g][d] = acc;
        sX[g][d] = x[(long)node * D + d];
    }
    __syncthreads();

    if (node < N_NODES) {
        float accO = sB[d];
        #pragma unroll
        for (int k = 0; k < D; ++k)
            accO += sAgg[g][k] * sWrelT[k * D + d] + sX[g][k] * sWrootT[k * D + d];
        h[(long)node * D + d] = accO > 0.f ? accO : 0.f;
    }
}

// ---------------------------------------------------------------------------
// 5) Fused gather + GraphConv layer 2 (+ReLU) + fc1(+ReLU) + fc2:
// ---------------------------------------------------------------------------
__global__ __launch_bounds__(256) void gather_node2_kernel(
    const float* __restrict__ h1,
    const int* __restrict__ rowptr, const int* __restrict__ csr_src,
    const float* __restrict__ w_rel, const float* __restrict__ b_rel,
    const float* __restrict__ w_root,
    const float* __restrict__ fc1_w, const float* __restrict__ fc1_b,
    const float* __restrict__ fc2_w, const float* __restrict__ fc2_b,
    float* __restrict__ out) {
    __shared__ float sWrelT[D * D];
    __shared__ float sWrootT[D * D];
    __shared__ float sB[D];
    __shared__ float sF1w[8 * D];
    __shared__ float sF1b[8];
    __shared__ float sF2w[2 * 8];
    __shared__ float sF2b[2];
    __shared__ float sAgg[16][D + 1];
    __shared__ float sX[16][D + 1];
    __shared__ float sH2[16][D + 1];

    {
        int r = threadIdx.x >> 4, c = threadIdx.x & 15;
        sWrelT[c * D + r] = w_rel[r * D + c];
        sWrootT[c * D + r] = w_root[r * D + c];
        if (threadIdx.x < D) sB[threadIdx.x] = b_rel[threadIdx.x];
        if (threadIdx.x < 8 * D) sF1w[threadIdx.x] = fc1_w[threadIdx.x];
        if (threadIdx.x < 8) sF1b[threadIdx.x] = fc1_b[threadIdx.x];
        if (threadIdx.x < 16) sF2w[threadIdx.x] = fc2_w[threadIdx.x];
        if (threadIdx.x < 2) sF2b[threadIdx.x] = fc2_b[threadIdx.x];
    }
    __syncthreads();

    int g = threadIdx.x >> 4;
    int d = threadIdx.x & 15;
    int node = blockIdx.x * 16 + g;

    if (node < N_NODES) {
        int r0 = rowptr[node], r1 = rowptr[node + 1];
        float acc = 0.f;
        for (int j = r0; j < r1; ++j) {
            int s = csr_src[j];
            acc += h1[(long)s * D + d];
        }
        sAgg[g][d] = acc;
        sX[g][d] = h1[(long)node * D + d];
    }
    __syncthreads();

    if (node < N_NODES) {
        float accO = sB[d];
        #pragma unroll
        for (int k = 0; k < D; ++k)
            accO += sAgg[g][k] * sWrelT[k * D + d] + sX[g][k] * sWrootT[k * D + d];
        sH2[g][d] = accO > 0.f ? accO : 0.f;
    }
    __syncthreads();

    if (node < N_NODES && d < 2) {
        float h3[8];
        #pragma unroll
        for (int j = 0; j < 8; ++j) {
            float acc = sF1b[j];
            #pragma unroll
            for (int k = 0; k < D; ++k) acc += sH2[g][k] * sF1w[j * D + k];
            h3[j] = acc > 0.f ? acc : 0.f;
        }
        float o = sF2b[d];
        #pragma unroll
        for (int j = 0; j < 8; ++j) o += h3[j] * sF2w[d * 8 + j];
        out[(long)node * 2 + d] = o;
    }
}

extern "C" void kernel_launch(void* const* d_in, const int* in_sizes, int n_in,
                              void* d_out, int out_size, void* d_ws, size_t ws_size,
                              hipStream_t stream) {
    const float* x          = (const float*)d_in[0];
    const int*   edge_index = (const int*)d_in[1];
    const float* c1_wrel    = (const float*)d_in[2];
    const float* c1_brel    = (const float*)d_in[3];
    const float* c1_wroot   = (const float*)d_in[4];
    const float* c2_wrel    = (const float*)d_in[5];
    const float* c2_brel    = (const float*)d_in[6];
    const float* c2_wroot   = (const float*)d_in[7];
    const float* fc1_w      = (const float*)d_in[8];
    const float* fc1_b      = (const float*)d_in[9];
    const float* fc2_w      = (const float*)d_in[10];
    const float* fc2_b      = (const float*)d_in[11];
    float* out = (float*)d_out;

    // Workspace layout (4-byte units):
    //   csr_src  [N_EDGES]        20 MB
    //   rowptr   [N_NODES+1]       2 MB
    //   cursor   [N_NODES]         2 MB
    //   deg      [N_NODES]         2 MB   (also reused as 'scanned')
    //   scanned  [N_NODES]         2 MB
    //   partials [512]             2 KB
    //   h1       [N_NODES*D]      32 MB   -> total ~60 MB
    int* csr_src  = (int*)d_ws;
    int* rowptr   = csr_src + N_EDGES;
    int* cursor   = rowptr + (N_NODES + 1);
    int* deg      = cursor + N_NODES;
    int* scanned  = deg + N_NODES;
    int* partials = scanned + N_NODES;
    float* h1     = (float*)(partials + 512);

    const int BLK = 256;
    int edge_blocks = (N_EDGES + BLK - 1) / BLK;
    int node_blocks16 = (N_NODES + 15) / 16;
    int node_blocks256 = (N_NODES + BLK - 1) / BLK;

    // --- Build CSR (amortized over both layers) ---
    hipMemsetAsync(deg, 0, N_NODES * sizeof(int), stream);
    hist_kernel<<<edge_blocks, BLK, 0, stream>>>(edge_index, deg);
    scan_blocks_kernel<<<NSCAN_BLOCKS, BLK, 0, stream>>>(deg, scanned, partials);
    scan_partials_kernel<<<1, 512, 0, stream>>>(partials);
    scan_add_kernel<<<node_blocks256, BLK, 0, stream>>>(scanned, partials, rowptr, cursor);
    reorder_kernel<<<edge_blocks, BLK, 0, stream>>>(edge_index, cursor, csr_src);

    // --- Layer 1 (fused gather + conv1 + relu) ---
    gather_node1_kernel<<<node_blocks16, BLK, 0, stream>>>(
        x, rowptr, csr_src, c1_wrel, c1_brel, c1_wroot, h1);

    // --- Layer 2 (fused gather + conv2 + relu + fc1 + relu + fc2) ---
    gather_node2_kernel<<<node_blocks16, BLK, 0, stream>>>(
        h1, rowptr, csr_src, c2_wrel, c2_brel, c2_wroot,
        fc1_w, fc1_b, fc2_w, fc2_b, out);
}

// Round 4
// 661.040 us; speedup vs baseline: 1.9985x; 1.9985x over previous
//
#include <hip/hip_runtime.h>
#include <hip/hip_fp16.h>

#define N_NODES 500000
#define N_EDGES 5000000
#define D 16

// ---------------------------------------------------------------------------
// Scatter layer 1: agg[dst][p] += half2(x[src][2p..2p+1])
// One thread per (edge, half2-pair): tid = e*8 + p. 8 lanes/edge: coalesced
// 64B float2 gather of x[src], one packed-f16 atomic (1 dword RMW) each.
// ---------------------------------------------------------------------------
__global__ __launch_bounds__(256) void scatter1_kernel(
    const float* __restrict__ x,
    const int* __restrict__ edge_index,   // [2, E]
    __half2* __restrict__ agg) {          // [N][8]
    long tid = (long)blockIdx.x * 256 + threadIdx.x;
    if (tid >= (long)N_EDGES * 8) return;
    int e = (int)(tid >> 3);
    int p = (int)(tid & 7);
    int s = edge_index[e];
    int t = edge_index[N_EDGES + e];
    float2 v = ((const float2*)(x + (long)s * D))[p];
    unsafeAtomicAdd(&agg[(long)t * 8 + p], __float22half2_rn(v));
}

// ---------------------------------------------------------------------------
// Scatter layer 2: agg[dst][p] += h1[src][p]   (h1 already f16-packed)
// ---------------------------------------------------------------------------
__global__ __launch_bounds__(256) void scatter2_kernel(
    const __half2* __restrict__ h1,       // [N][8]
    const int* __restrict__ edge_index,
    __half2* __restrict__ agg) {
    long tid = (long)blockIdx.x * 256 + threadIdx.x;
    if (tid >= (long)N_EDGES * 8) return;
    int e = (int)(tid >> 3);
    int p = (int)(tid & 7);
    int s = edge_index[e];
    int t = edge_index[N_EDGES + e];
    __half2 v = h1[(long)s * 8 + p];
    unsafeAtomicAdd(&agg[(long)t * 8 + p], v);
}

// ---------------------------------------------------------------------------
// Node layer 1: h1[i] = f16( relu(agg[i] @ Wrel^T + b + x[i] @ Wroot^T) )
// One node per thread; weights broadcast from LDS.
// ---------------------------------------------------------------------------
__global__ __launch_bounds__(256) void node1_kernel(
    const float* __restrict__ x,
    const __half2* __restrict__ agg,
    const float* __restrict__ w_rel,   // [D][D]
    const float* __restrict__ b_rel,
    const float* __restrict__ w_root,
    __half2* __restrict__ h1) {
    __shared__ float sWrel[D * D];
    __shared__ float sWroot[D * D];
    __shared__ float sB[D];
    for (int i = threadIdx.x; i < D * D; i += blockDim.x) {
        sWrel[i] = w_rel[i];
        sWroot[i] = w_root[i];
    }
    if (threadIdx.x < D) sB[threadIdx.x] = b_rel[threadIdx.x];
    __syncthreads();

    int i = blockIdx.x * blockDim.x + threadIdx.x;
    if (i >= N_NODES) return;

    float a[D], xi[D];
    {
        __half2 hrow[8];
        const float4* ap = (const float4*)(agg + (long)i * 8);
        *(float4*)&hrow[0] = ap[0];
        *(float4*)&hrow[4] = ap[1];
        #pragma unroll
        for (int q = 0; q < 8; ++q) {
            float2 f = __half22float2(hrow[q]);
            a[2 * q] = f.x; a[2 * q + 1] = f.y;
        }
        const float4* xp = (const float4*)(x + (long)i * D);
        #pragma unroll
        for (int q = 0; q < 4; ++q) {
            float4 xv = xp[q];
            xi[q * 4 + 0] = xv.x; xi[q * 4 + 1] = xv.y;
            xi[q * 4 + 2] = xv.z; xi[q * 4 + 3] = xv.w;
        }
    }

    __half2 hout[8];
    #pragma unroll
    for (int q = 0; q < 8; ++q) {
        float o0, o1;
        #pragma unroll
        for (int r = 0; r < 2; ++r) {
            int dd = 2 * q + r;
            float acc = sB[dd];
            #pragma unroll
            for (int k = 0; k < D; ++k)
                acc += a[k] * sWrel[dd * D + k] + xi[k] * sWroot[dd * D + k];
            acc = acc > 0.f ? acc : 0.f;
            if (r == 0) o0 = acc; else o1 = acc;
        }
        hout[q] = __float22half2_rn(make_float2(o0, o1));
    }
    float4* hp = (float4*)(h1 + (long)i * 8);
    hp[0] = *(float4*)&hout[0];
    hp[1] = *(float4*)&hout[4];
}

// ---------------------------------------------------------------------------
// Node layer 2 + head: h2 = relu(agg2 @ W2rel^T + b2 + h1 @ W2root^T)
//                      out = relu(h2 @ fc1^T + b1) @ fc2^T + b2
// ---------------------------------------------------------------------------
__global__ __launch_bounds__(256) void node2_kernel(
    const __half2* __restrict__ h1,
    const __half2* __restrict__ agg,
    const float* __restrict__ w_rel,
    const float* __restrict__ b_rel,
    const float* __restrict__ w_root,
    const float* __restrict__ fc1_w,  // [8][16]
    const float* __restrict__ fc1_b,
    const float* __restrict__ fc2_w,  // [2][8]
    const float* __restrict__ fc2_b,
    float* __restrict__ out) {
    __shared__ float sWrel[D * D];
    __shared__ float sWroot[D * D];
    __shared__ float sB[D];
    __shared__ float sF1w[8 * D];
    __shared__ float sF1b[8];
    __shared__ float sF2w[2 * 8];
    __shared__ float sF2b[2];
    for (int i = threadIdx.x; i < D * D; i += blockDim.x) {
        sWrel[i] = w_rel[i];
        sWroot[i] = w_root[i];
    }
    if (threadIdx.x < D) sB[threadIdx.x] = b_rel[threadIdx.x];
    if (threadIdx.x < 8 * D) sF1w[threadIdx.x] = fc1_w[threadIdx.x];
    if (threadIdx.x < 8) sF1b[threadIdx.x] = fc1_b[threadIdx.x];
    if (threadIdx.x < 16) sF2w[threadIdx.x] = fc2_w[threadIdx.x];
    if (threadIdx.x < 2) sF2b[threadIdx.x] = fc2_b[threadIdx.x];
    __syncthreads();

    int i = blockIdx.x * blockDim.x + threadIdx.x;
    if (i >= N_NODES) return;

    float a[D], xi[D];
    {
        __half2 hrow[8];
        const float4* ap = (const float4*)(agg + (long)i * 8);
        *(float4*)&hrow[0] = ap[0];
        *(float4*)&hrow[4] = ap[1];
        #pragma unroll
        for (int q = 0; q < 8; ++q) {
            float2 f = __half22float2(hrow[q]);
            a[2 * q] = f.x; a[2 * q + 1] = f.y;
        }
        const float4* xp = (const float4*)(h1 + (long)i * 8);
        *(float4*)&hrow[0] = xp[0];
        *(float4*)&hrow[4] = xp[1];
        #pragma unroll
        for (int q = 0; q < 8; ++q) {
            float2 f = __half22float2(hrow[q]);
            xi[2 * q] = f.x; xi[2 * q + 1] = f.y;
        }
    }

    float h2[D];
    #pragma unroll
    for (int dd = 0; dd < D; ++dd) {
        float acc = sB[dd];
        #pragma unroll
        for (int k = 0; k < D; ++k)
            acc += a[k] * sWrel[dd * D + k] + xi[k] * sWroot[dd * D + k];
        h2[dd] = acc > 0.f ? acc : 0.f;
    }

    float h3[8];
    #pragma unroll
    for (int j = 0; j < 8; ++j) {
        float acc = sF1b[j];
        #pragma unroll
        for (int k = 0; k < D; ++k) acc += h2[k] * sF1w[j * D + k];
        h3[j] = acc > 0.f ? acc : 0.f;
    }

    float2 o;
    {
        float acc0 = sF2b[0], acc1 = sF2b[1];
        #pragma unroll
        for (int j = 0; j < 8; ++j) {
            acc0 += h3[j] * sF2w[0 * 8 + j];
            acc1 += h3[j] * sF2w[1 * 8 + j];
        }
        o.x = acc0;
        o.y = acc1;
    }
    ((float2*)out)[i] = o;
}

extern "C" void kernel_launch(void* const* d_in, const int* in_sizes, int n_in,
                              void* d_out, int out_size, void* d_ws, size_t ws_size,
                              hipStream_t stream) {
    const float* x          = (const float*)d_in[0];
    const int*   edge_index = (const int*)d_in[1];
    const float* c1_wrel    = (const float*)d_in[2];
    const float* c1_brel    = (const float*)d_in[3];
    const float* c1_wroot   = (const float*)d_in[4];
    const float* c2_wrel    = (const float*)d_in[5];
    const float* c2_brel    = (const float*)d_in[6];
    const float* c2_wroot   = (const float*)d_in[7];
    const float* fc1_w      = (const float*)d_in[8];
    const float* fc1_b      = (const float*)d_in[9];
    const float* fc2_w      = (const float*)d_in[10];
    const float* fc2_b      = (const float*)d_in[11];
    float* out = (float*)d_out;

    // Workspace: agg [N*8 half2 = 16 MB], h1 [N*8 half2 = 16 MB]
    __half2* agg = (__half2*)d_ws;
    __half2* h1  = agg + (long)N_NODES * 8;
    size_t agg_bytes = (size_t)N_NODES * 8 * sizeof(__half2);

    const int BLK = 256;
    long scatter_total = (long)N_EDGES * 8;
    int scatter_blocks = (int)((scatter_total + BLK - 1) / BLK);
    int node_blocks = (N_NODES + BLK - 1) / BLK;

    // Layer 1
    hipMemsetAsync(agg, 0, agg_bytes, stream);
    scatter1_kernel<<<scatter_blocks, BLK, 0, stream>>>(x, edge_index, agg);
    node1_kernel<<<node_blocks, BLK, 0, stream>>>(x, agg, c1_wrel, c1_brel, c1_wroot, h1);

    // Layer 2 + head
    hipMemsetAsync(agg, 0, agg_bytes, stream);
    scatter2_kernel<<<scatter_blocks, BLK, 0, stream>>>(h1, edge_index, agg);
    node2_kernel<<<node_blocks, BLK, 0, stream>>>(h1, agg, c2_wrel, c2_brel, c2_wroot,
                                                  fc1_w, fc1_b, fc2_w, fc2_b, out);
}